// Round 11
// baseline (313.506 us; speedup 1.0000x reference)
//
#include <hip/hip_runtime.h>
#include <math.h>

typedef unsigned short u16;
typedef unsigned int u32;
typedef __bf16 bf16x8_t __attribute__((ext_vector_type(8)));
typedef float f32x4_t __attribute__((ext_vector_type(4)));

__device__ __forceinline__ u16 f2bf(float f) {
  __bf16 b = (__bf16)f;
  return __builtin_bit_cast(u16, b);
}

__device__ __forceinline__ void gld16(const void* g, void* l) {
  __builtin_amdgcn_global_load_lds(
      (const __attribute__((address_space(1))) void*)g,
      (__attribute__((address_space(3))) void*)l, 16, 0, 0);
}

// tanh-form GELU via rcp: gelu = v - v*rcp(e^{2z}+1). Correct limits at +/-inf.
__device__ __forceinline__ float gelu_f(float v) {
  float z = 0.7978845608028654f * v * fmaf(0.044715f, v * v, 1.0f);
  float t = __builtin_amdgcn_exp2f(2.8853900817779268f * z);   // e^{2z}
  float r = __builtin_amdgcn_rcpf(t + 1.0f);
  return v - v * r;
}

__device__ __forceinline__ int swz8(int bid, int nwg) {
  int cpx = nwg >> 3;                 // requires nwg % 8 == 0
  return (bid & 7) * cpx + (bid >> 3);
}

// ---------------------------------------------------------------------------
// cast fp32 -> bf16 (w1)
__global__ __launch_bounds__(256) void cast_kernel(const float* __restrict__ src,
                                                   u16* __restrict__ dst, int n) {
  int i = (blockIdx.x * 256 + threadIdx.x) * 4;
  if (i < n) {
    float4 v = *(const float4*)(src + i);
    uint2 o;
    o.x = (u32)f2bf(v.x) | ((u32)f2bf(v.y) << 16);
    o.y = (u32)f2bf(v.z) | ((u32)f2bf(v.w) << 16);
    *(uint2*)(dst + i) = o;
  }
}

// ---------------------------------------------------------------------------
// b2ob[c] = b2[c] + sum_i grn_b[i]*w2[c][i]
__global__ __launch_bounds__(64) void b2ob_kernel(const float* __restrict__ w2,
                                                  const float* __restrict__ grn_b,
                                                  const float* __restrict__ b2,
                                                  float* __restrict__ out) {
  int c = blockIdx.x;
  int l = threadIdx.x;
  float p = 0.f;
  for (int i = l; i < 1536; i += 64) p += grn_b[i] * w2[(size_t)c * 1536 + i];
  #pragma unroll
  for (int s = 32; s; s >>= 1) p += __shfl_xor(p, s);
  if (l == 0) out[c] = b2[c] + p;
}

// ---------------------------------------------------------------------------
// depthwise conv (K=7, pad 3) + LayerNorm over C, output bf16 [B*T][512]
__global__ __launch_bounds__(512, 4) void conv_ln_kernel(const float* __restrict__ X,
                                                         const float* __restrict__ Wd,
                                                         const float* __restrict__ bd,
                                                         const float* __restrict__ lng,
                                                         const float* __restrict__ lnb,
                                                         u16* __restrict__ Y) {
  __shared__ float ystage[16 * 516];
  __shared__ float mu_s[16], rs_s[16];

  const int c = threadIdx.x;
  const int b = blockIdx.y;
  const int t0 = blockIdx.x * 64;

  const float* xr = X + ((size_t)b * 512 + c) * 2048;
  float wr[7];
  #pragma unroll
  for (int k = 0; k < 7; ++k) wr[k] = Wd[c * 7 + k];
  const float bdv = bd[c];
  const float lg = lng[c];
  const float lb = lnb[c];

  for (int ch = 0; ch < 4; ++ch) {
    const int tc0 = t0 + ch * 16;
    const int g = tc0 - 4;
    float w[24];
    if (g >= 0 && g + 24 <= 2048) {
      #pragma unroll
      for (int q = 0; q < 6; ++q) {
        float4 v = *(const float4*)(xr + g + q * 4);
        w[q * 4 + 0] = v.x; w[q * 4 + 1] = v.y;
        w[q * 4 + 2] = v.z; w[q * 4 + 3] = v.w;
      }
    } else {
      #pragma unroll
      for (int j = 0; j < 24; ++j) {
        int tt = g + j;
        w[j] = (tt >= 0 && tt < 2048) ? xr[tt] : 0.f;
      }
    }
    float outv[16];
    #pragma unroll
    for (int i = 0; i < 16; ++i) {
      float a = bdv;
      #pragma unroll
      for (int k = 0; k < 7; ++k) a = fmaf(w[i + 1 + k], wr[k], a);
      outv[i] = a;
      ystage[i * 516 + c] = a;
    }
    __syncthreads();
    {
      int r = c >> 5, cl = c & 31;
      float s = 0.f, q = 0.f;
      #pragma unroll
      for (int k = 0; k < 16; ++k) {
        float v = ystage[r * 516 + cl + k * 32];
        s += v; q += v * v;
      }
      #pragma unroll
      for (int m = 16; m; m >>= 1) { s += __shfl_xor(s, m); q += __shfl_xor(q, m); }
      if (cl == 0) {
        float mu = s * (1.f / 512.f);
        float var = q * (1.f / 512.f) - mu * mu;
        mu_s[r] = mu;
        rs_s[r] = rsqrtf(var + 1e-6f);
      }
    }
    __syncthreads();
    #pragma unroll
    for (int i = 0; i < 16; ++i) {
      float v = (outv[i] - mu_s[i]) * rs_s[i] * lg + lb;
      Y[(size_t)(b * 2048 + tc0 + i) * 512 + c] = f2bf(v);
    }
  }
}

// ---------------------------------------------------------------------------
// GRN scale: s[b][i] = 1 + grn_g[i]*gx/(mean(gx)+1e-6)
__global__ __launch_bounds__(256) void grn_kernel(const float* __restrict__ gsum,
                                                  const float* __restrict__ grn_g,
                                                  float* __restrict__ svec) {
  __shared__ float red[256];
  int b = blockIdx.x, tid = threadIdx.x;
  float gx[6];
  float part = 0.f;
  #pragma unroll
  for (int it = 0; it < 6; ++it) {
    int i = it * 256 + tid;
    gx[it] = sqrtf(gsum[b * 1536 + i]);
    part += gx[it];
  }
  red[tid] = part;
  __syncthreads();
  for (int s = 128; s; s >>= 1) {
    if (tid < s) red[tid] += red[tid + s];
    __syncthreads();
  }
  float inv = 1.0f / (red[0] * (1.f / 1536.f) + 1e-6f);
  #pragma unroll
  for (int it = 0; it < 6; ++it) {
    int i = it * 256 + tid;
    svec[b * 1536 + i] = 1.0f + grn_g[i] * gx[it] * inv;
  }
}

// ---------------------------------------------------------------------------
// w2s[b][c][i] = bf16( w2[c][i] * svec[b][i] )
__global__ __launch_bounds__(256) void w2s_kernel(const float* __restrict__ w2,
                                                  const float* __restrict__ svec,
                                                  u16* __restrict__ out) {
  size_t e0 = ((size_t)blockIdx.x * 256 + threadIdx.x) * 8;  // flat into [16][512][1536]
  int i = (int)(e0 % 1536);
  size_t bc = e0 / 1536;
  int b = (int)(bc >> 9);
  size_t widx = (bc & 511) * 1536 + i;
  float4 wa = *(const float4*)(w2 + widx);
  float4 wb = *(const float4*)(w2 + widx + 4);
  float4 sa = *(const float4*)(svec + b * 1536 + i);
  float4 sb = *(const float4*)(svec + b * 1536 + i + 4);
  uint4 o;
  o.x = (u32)f2bf(wa.x * sa.x) | ((u32)f2bf(wa.y * sa.y) << 16);
  o.y = (u32)f2bf(wa.z * sa.z) | ((u32)f2bf(wa.w * sa.w) << 16);
  o.z = (u32)f2bf(wb.x * sb.x) | ((u32)f2bf(wb.y * sb.y) << 16);
  o.w = (u32)f2bf(wb.z * sb.z) | ((u32)f2bf(wb.w * sb.w) << 16);
  *(uint4*)(out + e0) = o;
}

// ---------------------------------------------------------------------------
// 128x128-tile K-loop, REG-B + CHUNKED-LDS-A:
//   B NEVER touches LDS: each wave loads its B fragments straight from
//   global (w1b / w2s panels are L2-resident; wm-duplicate waves read the
//   SAME addresses -> L1-served). A staged into LDS 256 K-elems at a time
//   (64KB chunk, 16 gld16/thread), then 4 barrier-free steps consume it.
//   Per K-128: 1 barrier-pair per 256k vs R7's 4 -> 4x fewer barriers; per
//   step LDS traffic halves (no B write/read). LDS = 64KB -> 2 blocks/CU:
//   sibling block's K-loop covers this block's stage/epilogue phases.
//   A swizzle: 16B-chunk index ^= (row&7) within each aligned 8-group;
//   realized by pre-swizzled per-lane GLOBAL source (linear gld16 dest) and
//   the matching XOR on ds_read (0-conflict scheme verified R5).
template<int KD, int NC>
__device__ __forceinline__ void gemm_kloop(const u16* __restrict__ Ag,
                                           const u16* __restrict__ Bg,
                                           u16* lds,
                                           f32x4_t (&acc)[4][4]) {
  const int tid = threadIdx.x;
  const int l = tid & 63, l15 = l & 15, lq = l >> 4;
  const int w = tid >> 6;                         // 0..3
  const int wm = w >> 1, wn = w & 1;
  const int lrow = l >> 5;                        // 0/1: row within pair
  const int lchunk = l & 31;                      // 16B chunk within 256-col row

  // per-lane B base: rows by wn/l15, k by lq (per-wave reg fragments)
  const u16* Bl = Bg + (size_t)(wn * 64 + l15) * KD + lq * 8;

  for (int c = 0; c < NC; ++c) {
    // STAGE A chunk c: 128 rows x 256 k (64KB); each gld16 covers 2 rows
    #pragma unroll
    for (int i = 0; i < 16; ++i) {
      const int r = w * 32 + i * 2 + lrow;
      const int srcCol = c * 256 + ((lchunk ^ (r & 7)) << 3);
      gld16(Ag + (size_t)r * KD + srcCol, lds + (w * 32 + i * 2) * 256);
    }
    __syncthreads();   // drains vmcnt: chunk visible
    #pragma unroll
    for (int s = 0; s < 4; ++s) {
      const int kb = c * 256 + s * 64;
      bf16x8_t bfr[4][2];
      #pragma unroll
      for (int g = 0; g < 4; ++g)
        #pragma unroll
        for (int kk = 0; kk < 2; ++kk)
          bfr[g][kk] = *(const bf16x8_t*)(Bl + (size_t)(g * 16) * KD + kb + kk * 32);
      bf16x8_t af[4][2];
      #pragma unroll
      for (int f = 0; f < 4; ++f) {
        const int Ra = wm * 64 + f * 16 + l15;
        #pragma unroll
        for (int kk = 0; kk < 2; ++kk) {
          const int ck = (s * 8 + kk * 4 + lq) ^ (Ra & 7);
          af[f][kk] = *(const bf16x8_t*)(lds + Ra * 256 + ck * 8);
        }
      }
      #pragma unroll
      for (int i = 0; i < 4; ++i)
        #pragma unroll
        for (int j = 0; j < 4; ++j)
          #pragma unroll
          for (int kk = 0; kk < 2; ++kk)
            acc[i][j] = __builtin_amdgcn_mfma_f32_16x16x32_bf16(af[i][kk], bfr[j][kk], acc[i][j], 0, 0, 0);
    }
    __syncthreads();   // all A-reads done before next chunk overwrites
  }
}

// ---------------------------------------------------------------------------
// GEMM1: h = gelu(y_ln . w1^T + b1), M=32768 K=512 N=1536; + gsum col sumsq
__global__ __launch_bounds__(256, 2) void gemm1_kernel(const u16* __restrict__ A,
                                                       const u16* __restrict__ Bw,
                                                       const float* __restrict__ b1,
                                                       u16* __restrict__ H,
                                                       float* __restrict__ gsum) {
  extern __shared__ __align__(16) u16 lds[];   // 64KB A-chunk; epi overlays 128x130 u16
  const int tid = threadIdx.x;
  const int l = tid & 63, l15 = l & 15, lq = l >> 4;
  const int w = tid >> 6, wm = w >> 1, wn = w & 1;
  const int wg = swz8(blockIdx.x, 3072);
  const int ntile = wg % 12, mtile = wg / 12;   // consecutive wg share A-panel (L2-hot)
  const int m0 = mtile * 128, n0 = ntile * 128;
  const int bidx = m0 >> 11;

  f32x4_t acc[4][4];
  #pragma unroll
  for (int i = 0; i < 4; ++i)
    #pragma unroll
    for (int j = 0; j < 4; ++j) {
      f32x4_t z = {0.f, 0.f, 0.f, 0.f};
      acc[i][j] = z;
    }

  gemm_kloop<512, 2>(A + (size_t)m0 * 512, Bw + (size_t)n0 * 512, lds, acc);

  float bj[4];
  #pragma unroll
  for (int nf = 0; nf < 4; ++nf) bj[nf] = b1[n0 + wn * 64 + nf * 16 + l15];

  float ss[4] = {0.f, 0.f, 0.f, 0.f};
  #pragma unroll
  for (int mf = 0; mf < 4; ++mf) {
    const int lr = wm * 64 + mf * 16 + lq * 4;
    #pragma unroll
    for (int nf = 0; nf < 4; ++nf) {
      const int cl = wn * 64 + nf * 16 + l15;
      #pragma unroll
      for (int r = 0; r < 4; ++r) {
        float g = gelu_f(acc[mf][nf][r] + bj[nf]);
        ss[nf] += g * g;
        lds[(lr + r) * 130 + cl] = f2bf(g);
      }
    }
  }
  #pragma unroll
  for (int nf = 0; nf < 4; ++nf) {
    float v = ss[nf];
    v += __shfl_xor(v, 16);
    v += __shfl_xor(v, 32);
    if (lq == 0) atomicAdd(&gsum[bidx * 1536 + n0 + wn * 64 + nf * 16 + l15], v);
  }
  __syncthreads();
  #pragma unroll
  for (int it = 0; it < 8; ++it) {
    int idx = it * 256 + tid;      // 0..2047 = 128 rows x 16 chunks
    int row = idx >> 4, ch = idx & 15;
    uint4 v = *(const uint4*)(lds + row * 130 + ch * 8);
    *(uint4*)(H + (size_t)(m0 + row) * 1536 + n0 + ch * 8) = v;
  }
}

// ---------------------------------------------------------------------------
// GEMM2: out[b][c][t] = x + h . w2s(b)^T + b2ob[c], M=32768 K=1536 N=512
__global__ __launch_bounds__(256, 2) void gemm2_kernel(const u16* __restrict__ Hm,
                                                       const u16* __restrict__ W2s,
                                                       const float* __restrict__ b2ob,
                                                       const float* __restrict__ X,
                                                       float* __restrict__ Out) {
  extern __shared__ __align__(16) u16 lds[];   // 64KB A-chunk; epi overlays [64][129] f32
  const int tid = threadIdx.x;
  const int l = tid & 63, l15 = l & 15, lq = l >> 4;
  const int w = tid >> 6, wm = w >> 1, wn = w & 1;
  const int wg = swz8(blockIdx.x, 1024);
  const int ntile = wg & 3, mtile = wg >> 2;
  const int m0 = mtile * 128, n0 = ntile * 128;
  const int bidx = m0 >> 11, t0 = m0 & 2047;

  f32x4_t acc[4][4];
  #pragma unroll
  for (int i = 0; i < 4; ++i)
    #pragma unroll
    for (int j = 0; j < 4; ++j) {
      f32x4_t z = {0.f, 0.f, 0.f, 0.f};
      acc[i][j] = z;
    }

  gemm_kloop<1536, 6>(Hm + (size_t)m0 * 1536,
                      W2s + ((size_t)bidx * 512 + n0) * 1536, lds, acc);

  // transpose epilogue: 2 halves of 64 t-rows; f32 stage [64][129] conflict-free
  float* st = (float*)lds;
  for (int half = 0; half < 2; ++half) {
    __syncthreads();
    if (wm == half) {
      #pragma unroll
      for (int mf = 0; mf < 4; ++mf) {
        const int lr = mf * 16 + lq * 4;
        #pragma unroll
        for (int nf = 0; nf < 4; ++nf) {
          const int cl = wn * 64 + nf * 16 + l15;
          #pragma unroll
          for (int r = 0; r < 4; ++r)
            st[(lr + r) * 129 + cl] = acc[mf][nf][r];
        }
      }
    }
    __syncthreads();
    const size_t obase = ((size_t)bidx * 512 + n0) * 2048 + (size_t)(t0 + half * 64 + l);
    #pragma unroll
    for (int cc = 0; cc < 32; ++cc) {
      const int c = w * 32 + cc;
      float v = st[l * 129 + c] + b2ob[n0 + c];
      size_t oi = obase + (size_t)c * 2048;
      Out[oi] = v + X[oi];
    }
  }
}

// ---------------------------------------------------------------------------
extern "C" void kernel_launch(void* const* d_in, const int* in_sizes, int n_in,
                              void* d_out, int out_size, void* d_ws, size_t ws_size,
                              hipStream_t stream) {
  const float* x     = (const float*)d_in[0];
  const float* dw_w  = (const float*)d_in[1];
  const float* dw_b  = (const float*)d_in[2];
  const float* ln_g  = (const float*)d_in[3];
  const float* ln_b  = (const float*)d_in[4];
  const float* w1    = (const float*)d_in[5];
  const float* b1    = (const float*)d_in[6];
  const float* grn_g = (const float*)d_in[7];
  const float* grn_b = (const float*)d_in[8];
  const float* w2    = (const float*)d_in[9];
  const float* b2    = (const float*)d_in[10];
  float* out = (float*)d_out;

  // workspace layout (w2s overlays y_ln: y_ln is dead after gemm1)
  u16* y_ln = (u16*)d_ws;                             // 32768*512 u16
  u16* w2s  = y_ln;                                   // 16*512*1536 u16
  u16* h    = y_ln + (size_t)32768 * 512;             // 32768*1536 u16
  u16* w1b  = h + (size_t)32768 * 1536;               // 1536*512 u16
  float* gsum = (float*)(w1b + (size_t)1536 * 512);   // 16*1536 f32
  float* svec = gsum + 16 * 1536;                     // 16*1536 f32
  float* b2ob = svec + 16 * 1536;                     // 512 f32

  (void)hipFuncSetAttribute((const void*)gemm1_kernel,
                            hipFuncAttributeMaxDynamicSharedMemorySize, 65536);
  (void)hipFuncSetAttribute((const void*)gemm2_kernel,
                            hipFuncAttributeMaxDynamicSharedMemorySize, 65536);

  hipMemsetAsync(gsum, 0, 16 * 1536 * sizeof(float), stream);
  cast_kernel<<<768, 256, 0, stream>>>(w1, w1b, 1536 * 512);
  b2ob_kernel<<<512, 64, 0, stream>>>(w2, grn_b, b2, b2ob);
  conv_ln_kernel<<<dim3(32, 16), 512, 0, stream>>>(x, dw_w, dw_b, ln_g, ln_b, y_ln);
  gemm1_kernel<<<3072, 256, 65536, stream>>>(y_ln, w1b, b1, h, gsum);
  grn_kernel<<<16, 256, 0, stream>>>(gsum, grn_g, svec);
  w2s_kernel<<<6144, 256, 0, stream>>>(w2, svec, w2s);
  gemm2_kernel<<<1024, 256, 65536, stream>>>(h, w2s, b2ob, x, out);
}

// Round 12
// 274.170 us; speedup vs baseline: 1.1435x; 1.1435x over previous
//
#include <hip/hip_runtime.h>
#include <math.h>

typedef unsigned short u16;
typedef unsigned int u32;
typedef __bf16 bf16x8_t __attribute__((ext_vector_type(8)));
typedef float f32x4_t __attribute__((ext_vector_type(4)));

__device__ __forceinline__ u16 f2bf(float f) {
  __bf16 b = (__bf16)f;
  return __builtin_bit_cast(u16, b);
}

__device__ __forceinline__ void gld16(const void* g, void* l) {
  __builtin_amdgcn_global_load_lds(
      (const __attribute__((address_space(1))) void*)g,
      (__attribute__((address_space(3))) void*)l, 16, 0, 0);
}

// tanh-form GELU via rcp: gelu = v - v*rcp(e^{2z}+1). Correct limits at +/-inf.
__device__ __forceinline__ float gelu_f(float v) {
  float z = 0.7978845608028654f * v * fmaf(0.044715f, v * v, 1.0f);
  float t = __builtin_amdgcn_exp2f(2.8853900817779268f * z);   // e^{2z}
  float r = __builtin_amdgcn_rcpf(t + 1.0f);
  return v - v * r;
}

__device__ __forceinline__ int swz8(int bid, int nwg) {
  int cpx = nwg >> 3;                 // requires nwg % 8 == 0
  return (bid & 7) * cpx + (bid >> 3);
}

// ---------------------------------------------------------------------------
// cast fp32 -> bf16 (w1)
__global__ __launch_bounds__(256) void cast_kernel(const float* __restrict__ src,
                                                   u16* __restrict__ dst, int n) {
  int i = (blockIdx.x * 256 + threadIdx.x) * 4;
  if (i < n) {
    float4 v = *(const float4*)(src + i);
    uint2 o;
    o.x = (u32)f2bf(v.x) | ((u32)f2bf(v.y) << 16);
    o.y = (u32)f2bf(v.z) | ((u32)f2bf(v.w) << 16);
    *(uint2*)(dst + i) = o;
  }
}

// ---------------------------------------------------------------------------
// b2ob[c] = b2[c] + sum_i grn_b[i]*w2[c][i]
__global__ __launch_bounds__(64) void b2ob_kernel(const float* __restrict__ w2,
                                                  const float* __restrict__ grn_b,
                                                  const float* __restrict__ b2,
                                                  float* __restrict__ out) {
  int c = blockIdx.x;
  int l = threadIdx.x;
  float p = 0.f;
  for (int i = l; i < 1536; i += 64) p += grn_b[i] * w2[(size_t)c * 1536 + i];
  #pragma unroll
  for (int s = 32; s; s >>= 1) p += __shfl_xor(p, s);
  if (l == 0) out[c] = b2[c] + p;
}

// ---------------------------------------------------------------------------
// depthwise conv (K=7, pad 3) + LayerNorm over C, output bf16 [B*T][512]
__global__ __launch_bounds__(512, 4) void conv_ln_kernel(const float* __restrict__ X,
                                                         const float* __restrict__ Wd,
                                                         const float* __restrict__ bd,
                                                         const float* __restrict__ lng,
                                                         const float* __restrict__ lnb,
                                                         u16* __restrict__ Y) {
  __shared__ float ystage[16 * 516];
  __shared__ float mu_s[16], rs_s[16];

  const int c = threadIdx.x;
  const int b = blockIdx.y;
  const int t0 = blockIdx.x * 64;

  const float* xr = X + ((size_t)b * 512 + c) * 2048;
  float wr[7];
  #pragma unroll
  for (int k = 0; k < 7; ++k) wr[k] = Wd[c * 7 + k];
  const float bdv = bd[c];
  const float lg = lng[c];
  const float lb = lnb[c];

  for (int ch = 0; ch < 4; ++ch) {
    const int tc0 = t0 + ch * 16;
    const int g = tc0 - 4;
    float w[24];
    if (g >= 0 && g + 24 <= 2048) {
      #pragma unroll
      for (int q = 0; q < 6; ++q) {
        float4 v = *(const float4*)(xr + g + q * 4);
        w[q * 4 + 0] = v.x; w[q * 4 + 1] = v.y;
        w[q * 4 + 2] = v.z; w[q * 4 + 3] = v.w;
      }
    } else {
      #pragma unroll
      for (int j = 0; j < 24; ++j) {
        int tt = g + j;
        w[j] = (tt >= 0 && tt < 2048) ? xr[tt] : 0.f;
      }
    }
    float outv[16];
    #pragma unroll
    for (int i = 0; i < 16; ++i) {
      float a = bdv;
      #pragma unroll
      for (int k = 0; k < 7; ++k) a = fmaf(w[i + 1 + k], wr[k], a);
      outv[i] = a;
      ystage[i * 516 + c] = a;
    }
    __syncthreads();
    {
      int r = c >> 5, cl = c & 31;
      float s = 0.f, q = 0.f;
      #pragma unroll
      for (int k = 0; k < 16; ++k) {
        float v = ystage[r * 516 + cl + k * 32];
        s += v; q += v * v;
      }
      #pragma unroll
      for (int m = 16; m; m >>= 1) { s += __shfl_xor(s, m); q += __shfl_xor(q, m); }
      if (cl == 0) {
        float mu = s * (1.f / 512.f);
        float var = q * (1.f / 512.f) - mu * mu;
        mu_s[r] = mu;
        rs_s[r] = rsqrtf(var + 1e-6f);
      }
    }
    __syncthreads();
    #pragma unroll
    for (int i = 0; i < 16; ++i) {
      float v = (outv[i] - mu_s[i]) * rs_s[i] * lg + lb;
      Y[(size_t)(b * 2048 + tc0 + i) * 512 + c] = f2bf(v);
    }
  }
}

// ---------------------------------------------------------------------------
// GRN scale: s[b][i] = 1 + grn_g[i]*gx/(mean(gx)+1e-6)
__global__ __launch_bounds__(256) void grn_kernel(const float* __restrict__ gsum,
                                                  const float* __restrict__ grn_g,
                                                  float* __restrict__ svec) {
  __shared__ float red[256];
  int b = blockIdx.x, tid = threadIdx.x;
  float gx[6];
  float part = 0.f;
  #pragma unroll
  for (int it = 0; it < 6; ++it) {
    int i = it * 256 + tid;
    gx[it] = sqrtf(gsum[b * 1536 + i]);
    part += gx[it];
  }
  red[tid] = part;
  __syncthreads();
  for (int s = 128; s; s >>= 1) {
    if (tid < s) red[tid] += red[tid + s];
    __syncthreads();
  }
  float inv = 1.0f / (red[0] * (1.f / 1536.f) + 1e-6f);
  #pragma unroll
  for (int it = 0; it < 6; ++it) {
    int i = it * 256 + tid;
    svec[b * 1536 + i] = 1.0f + grn_g[i] * gx[it] * inv;
  }
}

// ---------------------------------------------------------------------------
// w2s[b][c][i] = bf16( w2[c][i] * svec[b][i] )
__global__ __launch_bounds__(256) void w2s_kernel(const float* __restrict__ w2,
                                                  const float* __restrict__ svec,
                                                  u16* __restrict__ out) {
  size_t e0 = ((size_t)blockIdx.x * 256 + threadIdx.x) * 8;  // flat into [16][512][1536]
  int i = (int)(e0 % 1536);
  size_t bc = e0 / 1536;
  int b = (int)(bc >> 9);
  size_t widx = (bc & 511) * 1536 + i;
  float4 wa = *(const float4*)(w2 + widx);
  float4 wb = *(const float4*)(w2 + widx + 4);
  float4 sa = *(const float4*)(svec + b * 1536 + i);
  float4 sb = *(const float4*)(svec + b * 1536 + i + 4);
  uint4 o;
  o.x = (u32)f2bf(wa.x * sa.x) | ((u32)f2bf(wa.y * sa.y) << 16);
  o.y = (u32)f2bf(wa.z * sa.z) | ((u32)f2bf(wa.w * sa.w) << 16);
  o.z = (u32)f2bf(wb.x * sb.x) | ((u32)f2bf(wb.y * sb.y) << 16);
  o.w = (u32)f2bf(wb.z * sb.z) | ((u32)f2bf(wb.w * sb.w) << 16);
  *(uint4*)(out + e0) = o;
}

// ---------------------------------------------------------------------------
// 256x256-tile K-loop, 8 waves (2m x 4n), wave tile 128x64, acc[8][4].
// 32.8 FLOP per LDS byte (vs 21.8 at 128x128/4-wave): A-fragment reused
// across 4 n-frags in regs; block LDS traffic/step = 256KB per 8.4 MFLOP.
// T3-minimum cadence (R7 winner): STAGE(S+1) issued BEFORE compute(S); one
// barrier per step drains the prefetch AFTER the 64-MFMA window.
// LDS: 2 x (A 256x64 + B 256x64) u16 = 128KB -> 1 block/CU, 8 waves = 2/SIMD.
// XOR-swizzle: pre-swizzled global source + swizzled ds_read (R5-verified).
template<int KD>
__device__ __forceinline__ void gemm_kloop(const u16* __restrict__ Ag,
                                           const u16* __restrict__ Bg,
                                           u16* lds, int NT,
                                           f32x4_t (&acc)[8][4]) {
  const int tid = threadIdx.x;
  const int l = tid & 63, l15 = l & 15, lq = l >> 4;
  const int w = tid >> 6;                         // 0..7
  const int wm = w >> 2, wn = w & 3;              // 2m x 4n
  const int rin = tid >> 3;                       // 0..63
  const int cs = ((tid & 7) ^ (rin & 7)) << 3;    // pre-swizzled k-chunk (u16)
  const int wb = w * 512;                         // wave stage offset: 8 rows

  auto STAGE = [&](int buf, int kt) {
    u16* lA = lds + buf * 32768;
    u16* lB = lA + 16384;
    #pragma unroll
    for (int c = 0; c < 4; ++c)      // A: 256 rows, 4 sweeps of 64
      gld16(Ag + (size_t)(c * 64 + rin) * KD + kt + cs, lA + c * 4096 + wb);
    #pragma unroll
    for (int c = 0; c < 4; ++c)      // B: 256 rows
      gld16(Bg + (size_t)(c * 64 + rin) * KD + kt + cs, lB + c * 4096 + wb);
  };

  STAGE(0, 0);
  __syncthreads();

  for (int S = 0; S < NT; ++S) {
    const int cur = S & 1;
    if (S + 1 < NT) STAGE(cur ^ 1, (S + 1) * 64);   // prefetch next tile
    u16* lA = lds + cur * 32768;
    u16* lB = lA + 16384;
    bf16x8_t bfr[4][2];
    #pragma unroll
    for (int g = 0; g < 4; ++g) {
      const int Rb = wn * 64 + g * 16 + l15;
      #pragma unroll
      for (int kk = 0; kk < 2; ++kk)
        bfr[g][kk] = *(const bf16x8_t*)(lB + Rb * 64 + (((kk * 4 + lq) ^ (Rb & 7)) << 3));
    }
    #pragma unroll
    for (int i = 0; i < 8; ++i) {
      const int Ra = wm * 128 + i * 16 + l15;
      bf16x8_t a0 = *(const bf16x8_t*)(lA + Ra * 64 + ((lq ^ (Ra & 7)) << 3));
      bf16x8_t a1 = *(const bf16x8_t*)(lA + Ra * 64 + (((4 + lq) ^ (Ra & 7)) << 3));
      #pragma unroll
      for (int j = 0; j < 4; ++j) {
        acc[i][j] = __builtin_amdgcn_mfma_f32_16x16x32_bf16(a0, bfr[j][0], acc[i][j], 0, 0, 0);
        acc[i][j] = __builtin_amdgcn_mfma_f32_16x16x32_bf16(a1, bfr[j][1], acc[i][j], 0, 0, 0);
      }
    }
    __syncthreads();   // drains prefetch AFTER compute; protects buffer swap
  }
}

// ---------------------------------------------------------------------------
// GEMM1: h = gelu(y_ln . w1^T + b1), M=32768 K=512 N=1536; + gsum col sumsq
__global__ __launch_bounds__(512, 2) void gemm1_kernel(const u16* __restrict__ A,
                                                       const u16* __restrict__ Bw,
                                                       const float* __restrict__ b1,
                                                       u16* __restrict__ H,
                                                       float* __restrict__ gsum) {
  extern __shared__ __align__(16) u16 lds[];   // 128KB kloop; epi overlays [128][264] u16
  const int tid = threadIdx.x;
  const int l = tid & 63, l15 = l & 15, lq = l >> 4;
  const int w = tid >> 6, wm = w >> 2, wn = w & 3;
  const int wg = swz8(blockIdx.x, 768);
  const int ntile = wg % 6, mtile = wg / 6;   // consecutive wg share A-panel
  const int m0 = mtile * 256, n0 = ntile * 256;
  const int bidx = m0 >> 11;

  f32x4_t acc[8][4];
  #pragma unroll
  for (int i = 0; i < 8; ++i)
    #pragma unroll
    for (int j = 0; j < 4; ++j) {
      f32x4_t z = {0.f, 0.f, 0.f, 0.f};
      acc[i][j] = z;
    }

  gemm_kloop<512>(A + (size_t)m0 * 512, Bw + (size_t)n0 * 512, lds, 8, acc);

  const int coll = wn * 64 + l15;
  float bj[4];
  #pragma unroll
  for (int nf = 0; nf < 4; ++nf) bj[nf] = b1[n0 + coll + nf * 16];

  float ss[4] = {0.f, 0.f, 0.f, 0.f};
  for (int half = 0; half < 2; ++half) {
    __syncthreads();
    if (wm == half) {
      #pragma unroll
      for (int mf = 0; mf < 8; ++mf) {
        const int lr = mf * 16 + lq * 4;
        #pragma unroll
        for (int nf = 0; nf < 4; ++nf) {
          #pragma unroll
          for (int r = 0; r < 4; ++r) {
            float g = gelu_f(acc[mf][nf][r] + bj[nf]);
            ss[nf] += g * g;
            lds[(lr + r) * 264 + coll + nf * 16] = f2bf(g);
          }
        }
      }
    }
    __syncthreads();
    #pragma unroll
    for (int it = 0; it < 8; ++it) {
      int idx = it * 512 + tid;      // 0..4095 = 128 rows x 32 chunks
      int row = idx >> 5, ch = idx & 31;
      uint4 v = *(const uint4*)(lds + row * 264 + ch * 8);
      *(uint4*)(H + (size_t)(m0 + half * 128 + row) * 1536 + n0 + ch * 8) = v;
    }
  }
  // gsum: each wave's ss covers its own 128 rows; wm 0/1 add disjoint halves
  #pragma unroll
  for (int nf = 0; nf < 4; ++nf) {
    float v = ss[nf];
    v += __shfl_xor(v, 16);
    v += __shfl_xor(v, 32);
    if (lq == 0) atomicAdd(&gsum[bidx * 1536 + n0 + coll + nf * 16], v);
  }
}

// ---------------------------------------------------------------------------
// GEMM2: out[b][c][t] = x + h . w2s(b)^T + b2ob[c], M=32768 K=1536 N=512
__global__ __launch_bounds__(512, 2) void gemm2_kernel(const u16* __restrict__ Hm,
                                                       const u16* __restrict__ W2s,
                                                       const float* __restrict__ b2ob,
                                                       const float* __restrict__ X,
                                                       float* __restrict__ Out) {
  extern __shared__ __align__(16) u16 lds[];   // 128KB kloop; epi overlays [64][261] f32
  const int tid = threadIdx.x;
  const int l = tid & 63, l15 = l & 15, lq = l >> 4;
  const int w = tid >> 6, wm = w >> 2, wn = w & 3;
  const int wg = swz8(blockIdx.x, 256);
  const int ntile = wg & 1, mtile = wg >> 1;   // pairs share A-panel
  const int m0 = mtile * 256, n0 = ntile * 256;
  const int bidx = m0 >> 11, t0 = m0 & 2047;

  f32x4_t acc[8][4];
  #pragma unroll
  for (int i = 0; i < 8; ++i)
    #pragma unroll
    for (int j = 0; j < 4; ++j) {
      f32x4_t z = {0.f, 0.f, 0.f, 0.f};
      acc[i][j] = z;
    }

  gemm_kloop<1536>(Hm + (size_t)m0 * 1536,
                   W2s + ((size_t)bidx * 512 + n0) * 1536, lds, 24, acc);

  // transpose epilogue: 4 groups of 64 t-rows; f32 stage [64][261] (261%32=5,
  // gcd(5,32)=1 -> conflict-free column reads)
  float* st = (float*)lds;
  for (int grp = 0; grp < 4; ++grp) {
    __syncthreads();
    if (wm == (grp >> 1)) {
      #pragma unroll
      for (int m2 = 0; m2 < 4; ++m2) {
        const int mf = (grp & 1) * 4 + m2;
        const int lr = m2 * 16 + lq * 4;
        #pragma unroll
        for (int nf = 0; nf < 4; ++nf) {
          const int cl = wn * 64 + nf * 16 + l15;
          #pragma unroll
          for (int r = 0; r < 4; ++r)
            st[(lr + r) * 261 + cl] = acc[mf][nf][r];
        }
      }
    }
    __syncthreads();
    const size_t obase = ((size_t)bidx * 512 + n0) * 2048 + (size_t)(t0 + grp * 64 + l);
    #pragma unroll
    for (int cc = 0; cc < 32; ++cc) {
      const int c = w * 32 + cc;
      float v = st[l * 261 + c] + b2ob[n0 + c];
      size_t oi = obase + (size_t)c * 2048;
      Out[oi] = v + X[oi];
    }
  }
}

// ---------------------------------------------------------------------------
extern "C" void kernel_launch(void* const* d_in, const int* in_sizes, int n_in,
                              void* d_out, int out_size, void* d_ws, size_t ws_size,
                              hipStream_t stream) {
  const float* x     = (const float*)d_in[0];
  const float* dw_w  = (const float*)d_in[1];
  const float* dw_b  = (const float*)d_in[2];
  const float* ln_g  = (const float*)d_in[3];
  const float* ln_b  = (const float*)d_in[4];
  const float* w1    = (const float*)d_in[5];
  const float* b1    = (const float*)d_in[6];
  const float* grn_g = (const float*)d_in[7];
  const float* grn_b = (const float*)d_in[8];
  const float* w2    = (const float*)d_in[9];
  const float* b2    = (const float*)d_in[10];
  float* out = (float*)d_out;

  // workspace layout (w2s overlays y_ln: y_ln is dead after gemm1)
  u16* y_ln = (u16*)d_ws;                             // 32768*512 u16
  u16* w2s  = y_ln;                                   // 16*512*1536 u16
  u16* h    = y_ln + (size_t)32768 * 512;             // 32768*1536 u16
  u16* w1b  = h + (size_t)32768 * 1536;               // 1536*512 u16
  float* gsum = (float*)(w1b + (size_t)1536 * 512);   // 16*1536 f32
  float* svec = gsum + 16 * 1536;                     // 16*1536 f32
  float* b2ob = svec + 16 * 1536;                     // 512 f32

  (void)hipFuncSetAttribute((const void*)gemm1_kernel,
                            hipFuncAttributeMaxDynamicSharedMemorySize, 131072);
  (void)hipFuncSetAttribute((const void*)gemm2_kernel,
                            hipFuncAttributeMaxDynamicSharedMemorySize, 131072);

  hipMemsetAsync(gsum, 0, 16 * 1536 * sizeof(float), stream);
  cast_kernel<<<768, 256, 0, stream>>>(w1, w1b, 1536 * 512);
  b2ob_kernel<<<512, 64, 0, stream>>>(w2, grn_b, b2, b2ob);
  conv_ln_kernel<<<dim3(32, 16), 512, 0, stream>>>(x, dw_w, dw_b, ln_g, ln_b, y_ln);
  gemm1_kernel<<<768, 512, 131072, stream>>>(y_ln, w1b, b1, h, gsum);
  grn_kernel<<<16, 256, 0, stream>>>(gsum, grn_g, svec);
  w2s_kernel<<<6144, 256, 0, stream>>>(w2, svec, w2s);
  gemm2_kernel<<<256, 512, 131072, stream>>>(h, w2s, b2ob, x, out);
}

// Round 13
// 245.230 us; speedup vs baseline: 1.2784x; 1.1180x over previous
//
#include <hip/hip_runtime.h>
#include <math.h>

typedef unsigned short u16;
typedef unsigned int u32;
typedef __bf16 bf16x8_t __attribute__((ext_vector_type(8)));
typedef float f32x4_t __attribute__((ext_vector_type(4)));

__device__ __forceinline__ u16 f2bf(float f) {
  __bf16 b = (__bf16)f;
  return __builtin_bit_cast(u16, b);
}

__device__ __forceinline__ void gld16(const void* g, void* l) {
  __builtin_amdgcn_global_load_lds(
      (const __attribute__((address_space(1))) void*)g,
      (__attribute__((address_space(3))) void*)l, 16, 0, 0);
}

// tanh-form GELU via rcp: gelu = v - v*rcp(e^{2z}+1). Correct limits at +/-inf.
__device__ __forceinline__ float gelu_f(float v) {
  float z = 0.7978845608028654f * v * fmaf(0.044715f, v * v, 1.0f);
  float t = __builtin_amdgcn_exp2f(2.8853900817779268f * z);   // e^{2z}
  float r = __builtin_amdgcn_rcpf(t + 1.0f);
  return v - v * r;
}

__device__ __forceinline__ int swz8(int bid, int nwg) {
  int cpx = nwg >> 3;                 // requires nwg % 8 == 0
  return (bid & 7) * cpx + (bid >> 3);
}

// ---------------------------------------------------------------------------
// cast fp32 -> bf16 (w1)
__global__ __launch_bounds__(256) void cast_kernel(const float* __restrict__ src,
                                                   u16* __restrict__ dst, int n) {
  int i = (blockIdx.x * 256 + threadIdx.x) * 4;
  if (i < n) {
    float4 v = *(const float4*)(src + i);
    uint2 o;
    o.x = (u32)f2bf(v.x) | ((u32)f2bf(v.y) << 16);
    o.y = (u32)f2bf(v.z) | ((u32)f2bf(v.w) << 16);
    *(uint2*)(dst + i) = o;
  }
}

// ---------------------------------------------------------------------------
// b2ob[c] = b2[c] + sum_i grn_b[i]*w2[c][i]
__global__ __launch_bounds__(64) void b2ob_kernel(const float* __restrict__ w2,
                                                  const float* __restrict__ grn_b,
                                                  const float* __restrict__ b2,
                                                  float* __restrict__ out) {
  int c = blockIdx.x;
  int l = threadIdx.x;
  float p = 0.f;
  for (int i = l; i < 1536; i += 64) p += grn_b[i] * w2[(size_t)c * 1536 + i];
  #pragma unroll
  for (int s = 32; s; s >>= 1) p += __shfl_xor(p, s);
  if (l == 0) out[c] = b2[c] + p;
}

// ---------------------------------------------------------------------------
// depthwise conv (K=7, pad 3) + LayerNorm over C, output bf16 [B*T][512]
__global__ __launch_bounds__(512, 4) void conv_ln_kernel(const float* __restrict__ X,
                                                         const float* __restrict__ Wd,
                                                         const float* __restrict__ bd,
                                                         const float* __restrict__ lng,
                                                         const float* __restrict__ lnb,
                                                         u16* __restrict__ Y) {
  __shared__ float ystage[16 * 516];
  __shared__ float mu_s[16], rs_s[16];

  const int c = threadIdx.x;
  const int b = blockIdx.y;
  const int t0 = blockIdx.x * 64;

  const float* xr = X + ((size_t)b * 512 + c) * 2048;
  float wr[7];
  #pragma unroll
  for (int k = 0; k < 7; ++k) wr[k] = Wd[c * 7 + k];
  const float bdv = bd[c];
  const float lg = lng[c];
  const float lb = lnb[c];

  for (int ch = 0; ch < 4; ++ch) {
    const int tc0 = t0 + ch * 16;
    const int g = tc0 - 4;
    float w[24];
    if (g >= 0 && g + 24 <= 2048) {
      #pragma unroll
      for (int q = 0; q < 6; ++q) {
        float4 v = *(const float4*)(xr + g + q * 4);
        w[q * 4 + 0] = v.x; w[q * 4 + 1] = v.y;
        w[q * 4 + 2] = v.z; w[q * 4 + 3] = v.w;
      }
    } else {
      #pragma unroll
      for (int j = 0; j < 24; ++j) {
        int tt = g + j;
        w[j] = (tt >= 0 && tt < 2048) ? xr[tt] : 0.f;
      }
    }
    float outv[16];
    #pragma unroll
    for (int i = 0; i < 16; ++i) {
      float a = bdv;
      #pragma unroll
      for (int k = 0; k < 7; ++k) a = fmaf(w[i + 1 + k], wr[k], a);
      outv[i] = a;
      ystage[i * 516 + c] = a;
    }
    __syncthreads();
    {
      int r = c >> 5, cl = c & 31;
      float s = 0.f, q = 0.f;
      #pragma unroll
      for (int k = 0; k < 16; ++k) {
        float v = ystage[r * 516 + cl + k * 32];
        s += v; q += v * v;
      }
      #pragma unroll
      for (int m = 16; m; m >>= 1) { s += __shfl_xor(s, m); q += __shfl_xor(q, m); }
      if (cl == 0) {
        float mu = s * (1.f / 512.f);
        float var = q * (1.f / 512.f) - mu * mu;
        mu_s[r] = mu;
        rs_s[r] = rsqrtf(var + 1e-6f);
      }
    }
    __syncthreads();
    #pragma unroll
    for (int i = 0; i < 16; ++i) {
      float v = (outv[i] - mu_s[i]) * rs_s[i] * lg + lb;
      Y[(size_t)(b * 2048 + tc0 + i) * 512 + c] = f2bf(v);
    }
  }
}

// ---------------------------------------------------------------------------
// GRN scale: s[b][i] = 1 + grn_g[i]*gx/(mean(gx)+1e-6)
__global__ __launch_bounds__(256) void grn_kernel(const float* __restrict__ gsum,
                                                  const float* __restrict__ grn_g,
                                                  float* __restrict__ svec) {
  __shared__ float red[256];
  int b = blockIdx.x, tid = threadIdx.x;
  float gx[6];
  float part = 0.f;
  #pragma unroll
  for (int it = 0; it < 6; ++it) {
    int i = it * 256 + tid;
    gx[it] = sqrtf(gsum[b * 1536 + i]);
    part += gx[it];
  }
  red[tid] = part;
  __syncthreads();
  for (int s = 128; s; s >>= 1) {
    if (tid < s) red[tid] += red[tid + s];
    __syncthreads();
  }
  float inv = 1.0f / (red[0] * (1.f / 1536.f) + 1e-6f);
  #pragma unroll
  for (int it = 0; it < 6; ++it) {
    int i = it * 256 + tid;
    svec[b * 1536 + i] = 1.0f + grn_g[i] * gx[it] * inv;
  }
}

// ---------------------------------------------------------------------------
// w2s[b][c][i] = bf16( w2[c][i] * svec[b][i] )
__global__ __launch_bounds__(256) void w2s_kernel(const float* __restrict__ w2,
                                                  const float* __restrict__ svec,
                                                  u16* __restrict__ out) {
  size_t e0 = ((size_t)blockIdx.x * 256 + threadIdx.x) * 8;  // flat into [16][512][1536]
  int i = (int)(e0 % 1536);
  size_t bc = e0 / 1536;
  int b = (int)(bc >> 9);
  size_t widx = (bc & 511) * 1536 + i;
  float4 wa = *(const float4*)(w2 + widx);
  float4 wb = *(const float4*)(w2 + widx + 4);
  float4 sa = *(const float4*)(svec + b * 1536 + i);
  float4 sb = *(const float4*)(svec + b * 1536 + i + 4);
  uint4 o;
  o.x = (u32)f2bf(wa.x * sa.x) | ((u32)f2bf(wa.y * sa.y) << 16);
  o.y = (u32)f2bf(wa.z * sa.z) | ((u32)f2bf(wa.w * sa.w) << 16);
  o.z = (u32)f2bf(wb.x * sb.x) | ((u32)f2bf(wb.y * sb.y) << 16);
  o.w = (u32)f2bf(wb.z * sb.z) | ((u32)f2bf(wb.w * sb.w) << 16);
  *(uint4*)(out + e0) = o;
}

// ---------------------------------------------------------------------------
// 128x128-tile K-loop, BK=32, R7 prefetch cadence, 4 BLOCKS/CU:
//   dbuf = 2 x (A[128][32] + B[128][32]) u16 = 32KB -> with ~33KB total LDS
//   and VGPR<=128 (__launch_bounds__(256,4)) => 4 independent blocks/CU
//   (16 waves). R7's winning cadence kept verbatim: STAGE(S+1) issued BEFORE
//   compute(S); ONE barrier per step (prefetch drain lands after the compute
//   window). Sibling blocks' K-loops cover each other's barrier stalls —
//   combining R6's block-TLP (4 blk) with R7's prefetch-dbuf.
// Swizzle (64B rows): physical 16B-chunk = logical ^ ((row>>1)&3); realized
//   as pre-swizzled per-lane GLOBAL source + linear gld16 dest, matching XOR
//   on ds_read. Residual 2-way bank alias is free (m136).
template<int KD>
__device__ __forceinline__ void gemm_kloop(const u16* __restrict__ Ag,
                                           const u16* __restrict__ Bg,
                                           u16* lds, int NT,
                                           f32x4_t (&acc)[4][4]) {
  const int tid = threadIdx.x;
  const int l = tid & 63, l15 = l & 15, lq = l >> 4;   // lq: 16B chunk 0..3
  const int w = tid >> 6;                              // 0..3
  const int wm = w >> 1, wn = w & 1;
  const int sr = l >> 2;                               // stage row-in-16
  const int sc = l & 3;                                // stage phys chunk

  auto STAGE = [&](int buf, int kt) {
    u16* lA = lds + buf * 8192;     // A 4096 u16 + B 4096 u16 per buffer
    u16* lB = lA + 4096;
    #pragma unroll
    for (int i = 0; i < 2; ++i) {
      const int r = (w * 2 + i) * 16 + sr;
      const int gc = ((sc ^ ((r >> 1) & 3)) << 3);     // pre-swizzled source col
      gld16(Ag + (size_t)r * KD + kt + gc, lA + (w * 2 + i) * 512);
      gld16(Bg + (size_t)r * KD + kt + gc, lB + (w * 2 + i) * 512);
    }
  };

  STAGE(0, 0);
  __syncthreads();

  for (int S = 0; S < NT; ++S) {
    const int cur = S & 1;
    if (S + 1 < NT) STAGE(cur ^ 1, (S + 1) * 32);   // prefetch next tile
    u16* lA = lds + cur * 8192;
    u16* lB = lA + 4096;
    bf16x8_t af[4], bf[4];
    #pragma unroll
    for (int f = 0; f < 4; ++f) {
      const int Ra = wm * 64 + f * 16 + l15;
      const int Rb = wn * 64 + f * 16 + l15;
      af[f] = *(const bf16x8_t*)(lA + Ra * 32 + ((lq ^ ((Ra >> 1) & 3)) << 3));
      bf[f] = *(const bf16x8_t*)(lB + Rb * 32 + ((lq ^ ((Rb >> 1) & 3)) << 3));
    }
    #pragma unroll
    for (int i = 0; i < 4; ++i)
      #pragma unroll
      for (int j = 0; j < 4; ++j)
        acc[i][j] = __builtin_amdgcn_mfma_f32_16x16x32_bf16(af[i], bf[j], acc[i][j], 0, 0, 0);
    __syncthreads();   // drains prefetch AFTER compute; protects buffer swap
  }
}

// ---------------------------------------------------------------------------
// GEMM1: h = gelu(y_ln . w1^T + b1), M=32768 K=512 N=1536; + gsum col sumsq
__global__ __launch_bounds__(256, 4) void gemm1_kernel(const u16* __restrict__ A,
                                                       const u16* __restrict__ Bw,
                                                       const float* __restrict__ b1,
                                                       u16* __restrict__ H,
                                                       float* __restrict__ gsum) {
  extern __shared__ __align__(16) u16 lds[];   // 32KB kloop dbuf; epi overlays 128x130 u16
  const int tid = threadIdx.x;
  const int l = tid & 63, l15 = l & 15, lq = l >> 4;
  const int w = tid >> 6, wm = w >> 1, wn = w & 1;
  const int wg = swz8(blockIdx.x, 3072);
  const int ntile = wg % 12, mtile = wg / 12;   // consecutive wg share A-panel
  const int m0 = mtile * 128, n0 = ntile * 128;
  const int bidx = m0 >> 11;

  f32x4_t acc[4][4];
  #pragma unroll
  for (int i = 0; i < 4; ++i)
    #pragma unroll
    for (int j = 0; j < 4; ++j) {
      f32x4_t z = {0.f, 0.f, 0.f, 0.f};
      acc[i][j] = z;
    }

  gemm_kloop<512>(A + (size_t)m0 * 512, Bw + (size_t)n0 * 512, lds, 16, acc);

  float bj[4];
  #pragma unroll
  for (int nf = 0; nf < 4; ++nf) bj[nf] = b1[n0 + wn * 64 + nf * 16 + l15];

  float ss[4] = {0.f, 0.f, 0.f, 0.f};
  #pragma unroll
  for (int mf = 0; mf < 4; ++mf) {
    const int lr = wm * 64 + mf * 16 + lq * 4;
    #pragma unroll
    for (int nf = 0; nf < 4; ++nf) {
      const int cl = wn * 64 + nf * 16 + l15;
      #pragma unroll
      for (int r = 0; r < 4; ++r) {
        float g = gelu_f(acc[mf][nf][r] + bj[nf]);
        ss[nf] += g * g;
        lds[(lr + r) * 130 + cl] = f2bf(g);
      }
    }
  }
  #pragma unroll
  for (int nf = 0; nf < 4; ++nf) {
    float v = ss[nf];
    v += __shfl_xor(v, 16);
    v += __shfl_xor(v, 32);
    if (lq == 0) atomicAdd(&gsum[bidx * 1536 + n0 + wn * 64 + nf * 16 + l15], v);
  }
  __syncthreads();
  #pragma unroll
  for (int it = 0; it < 8; ++it) {
    int idx = it * 256 + tid;      // 0..2047 = 128 rows x 16 chunks
    int row = idx >> 4, ch = idx & 15;
    uint4 v = *(const uint4*)(lds + row * 130 + ch * 8);
    *(uint4*)(H + (size_t)(m0 + row) * 1536 + n0 + ch * 8) = v;
  }
}

// ---------------------------------------------------------------------------
// GEMM2: out[b][c][t] = x + h . w2s(b)^T + b2ob[c], M=32768 K=1536 N=512
__global__ __launch_bounds__(256, 4) void gemm2_kernel(const u16* __restrict__ Hm,
                                                       const u16* __restrict__ W2s,
                                                       const float* __restrict__ b2ob,
                                                       const float* __restrict__ X,
                                                       float* __restrict__ Out) {
  extern __shared__ __align__(16) u16 lds[];   // 32KB kloop dbuf; epi overlays [64][129] f32
  const int tid = threadIdx.x;
  const int l = tid & 63, l15 = l & 15, lq = l >> 4;
  const int w = tid >> 6, wm = w >> 1, wn = w & 1;
  const int wg = swz8(blockIdx.x, 1024);
  const int ntile = wg & 3, mtile = wg >> 2;
  const int m0 = mtile * 128, n0 = ntile * 128;
  const int bidx = m0 >> 11, t0 = m0 & 2047;

  f32x4_t acc[4][4];
  #pragma unroll
  for (int i = 0; i < 4; ++i)
    #pragma unroll
    for (int j = 0; j < 4; ++j) {
      f32x4_t z = {0.f, 0.f, 0.f, 0.f};
      acc[i][j] = z;
    }

  gemm_kloop<1536>(Hm + (size_t)m0 * 1536,
                   W2s + ((size_t)bidx * 512 + n0) * 1536, lds, 48, acc);

  // transpose epilogue: 2 halves of 64 t-rows; f32 stage [64][129] conflict-free
  float* st = (float*)lds;
  for (int half = 0; half < 2; ++half) {
    __syncthreads();
    if (wm == half) {
      #pragma unroll
      for (int mf = 0; mf < 4; ++mf) {
        const int lr = mf * 16 + lq * 4;
        #pragma unroll
        for (int nf = 0; nf < 4; ++nf) {
          const int cl = wn * 64 + nf * 16 + l15;
          #pragma unroll
          for (int r = 0; r < 4; ++r)
            st[(lr + r) * 129 + cl] = acc[mf][nf][r];
        }
      }
    }
    __syncthreads();
    const size_t obase = ((size_t)bidx * 512 + n0) * 2048 + (size_t)(t0 + half * 64 + l);
    #pragma unroll
    for (int cc = 0; cc < 32; ++cc) {
      const int c = w * 32 + cc;
      float v = st[l * 129 + c] + b2ob[n0 + c];
      size_t oi = obase + (size_t)c * 2048;
      Out[oi] = v + X[oi];
    }
  }
}

// ---------------------------------------------------------------------------
extern "C" void kernel_launch(void* const* d_in, const int* in_sizes, int n_in,
                              void* d_out, int out_size, void* d_ws, size_t ws_size,
                              hipStream_t stream) {
  const float* x     = (const float*)d_in[0];
  const float* dw_w  = (const float*)d_in[1];
  const float* dw_b  = (const float*)d_in[2];
  const float* ln_g  = (const float*)d_in[3];
  const float* ln_b  = (const float*)d_in[4];
  const float* w1    = (const float*)d_in[5];
  const float* b1    = (const float*)d_in[6];
  const float* grn_g = (const float*)d_in[7];
  const float* grn_b = (const float*)d_in[8];
  const float* w2    = (const float*)d_in[9];
  const float* b2    = (const float*)d_in[10];
  float* out = (float*)d_out;

  // workspace layout (w2s overlays y_ln: y_ln is dead after gemm1)
  u16* y_ln = (u16*)d_ws;                             // 32768*512 u16
  u16* w2s  = y_ln;                                   // 16*512*1536 u16
  u16* h    = y_ln + (size_t)32768 * 512;             // 32768*1536 u16
  u16* w1b  = h + (size_t)32768 * 1536;               // 1536*512 u16
  float* gsum = (float*)(w1b + (size_t)1536 * 512);   // 16*1536 f32
  float* svec = gsum + 16 * 1536;                     // 16*1536 f32
  float* b2ob = svec + 16 * 1536;                     // 512 f32

  (void)hipFuncSetAttribute((const void*)gemm1_kernel,
                            hipFuncAttributeMaxDynamicSharedMemorySize, 33536);
  (void)hipFuncSetAttribute((const void*)gemm2_kernel,
                            hipFuncAttributeMaxDynamicSharedMemorySize, 33536);

  hipMemsetAsync(gsum, 0, 16 * 1536 * sizeof(float), stream);
  cast_kernel<<<768, 256, 0, stream>>>(w1, w1b, 1536 * 512);
  b2ob_kernel<<<512, 64, 0, stream>>>(w2, grn_b, b2, b2ob);
  conv_ln_kernel<<<dim3(32, 16), 512, 0, stream>>>(x, dw_w, dw_b, ln_g, ln_b, y_ln);
  gemm1_kernel<<<3072, 256, 33536, stream>>>(y_ln, w1b, b1, h, gsum);
  grn_kernel<<<16, 256, 0, stream>>>(gsum, grn_g, svec);
  w2s_kernel<<<6144, 256, 0, stream>>>(w2, svec, w2s);
  gemm2_kernel<<<1024, 256, 33536, stream>>>(h, w2s, b2ob, x, out);
}